// Round 1
// baseline (210.103 us; speedup 1.0000x reference)
//
#include <hip/hip_runtime.h>
#include <math.h>

#define BATCH 4
#define NH    16
#define TQ    512
#define TM    512
#define DD    64
#define HID   16
#define TT    16          // T rows per workgroup
#define MB    32          // m chunk staged in LDS
#define QSTR  (DD + 4)    // 68: 16B-aligned rows, banks spread by 4*r
#define SSTR  (TM + 4)    // 516: 16B-aligned rows, <=2-way conflicts

__global__ __launch_bounds__(256, 2)
void msmha_kernel(const float* __restrict__ q,
                  const float* __restrict__ k,
                  const float* __restrict__ v,
                  const float* __restrict__ D_TM,
                  const float* __restrict__ m1w,
                  const float* __restrict__ m1b,
                  const float* __restrict__ m2w,
                  const float* __restrict__ m2b,
                  float* __restrict__ out) {
    __shared__ float qs[TT][QSTR];
    __shared__ float ks[MB][QSTR];
    __shared__ float scores[TT][SSTR];
    __shared__ float rowinv[TT];

    const int tid  = threadIdx.x;
    const int tile = blockIdx.x & 31;          // TQ/TT = 32 tiles
    const int bh   = blockIdx.x >> 5;
    const int h    = bh & (NH - 1);
    const int b    = bh >> 4;
    const int t0   = tile * TT;

    const size_t qbase = ((size_t)bh) * TQ * DD;
    const size_t kbase = ((size_t)bh) * TM * DD;

    // ---- per-head MLP weights: wave-uniform addresses -> scalar loads ----
    float w1d_[HID], w1s_[HID], b1_[HID], w2_[HID];
    {
        const float* w1p = m1w + (size_t)h * 2 * HID;
#pragma unroll
        for (int c = 0; c < HID; ++c) {
            w1d_[c] = w1p[c];
            w1s_[c] = w1p[HID + c];
            b1_[c]  = m1b[h * HID + c];
            w2_[c]  = m2w[h * HID + c];
        }
    }
    const float b2_ = m2b[h];

    // ---- stage q tile (16x64 floats = exactly 256 float4s) ----
    {
        const int rr  = tid >> 4;
        const int dd4 = (tid & 15) << 2;
        *(float4*)&qs[rr][dd4] =
            *(const float4*)(q + qbase + (size_t)(t0 + rr) * DD + dd4);
    }
    __syncthreads();

    const int r  = tid >> 4;   // 0..15 : local row
    const int ms = tid & 15;   // 0..15 : m sub-lane

    const float* Drow = D_TM + ((size_t)b * TQ + t0 + r) * TM;

    // ---- scores + fused MLP, chunked over m ----
    for (int mc = 0; mc < TM / MB; ++mc) {
        const int mbase = mc * MB;
        // stage k chunk: 32x64 floats = 512 float4s, 2 per thread
#pragma unroll
        for (int i = tid; i < MB * DD / 4; i += 256) {
            const int mm  = i >> 4;
            const int dd4 = (i & 15) << 2;
            *(float4*)&ks[mm][dd4] =
                *(const float4*)(k + kbase + (size_t)(mbase + mm) * DD + dd4);
        }
        __syncthreads();

        float acc0 = 0.f, acc1 = 0.f;
#pragma unroll
        for (int dq = 0; dq < DD / 4; ++dq) {
            const float4 qv = *(const float4*)&qs[r][dq * 4];
            const float4 ka = *(const float4*)&ks[ms][dq * 4];
            const float4 kb = *(const float4*)&ks[ms + 16][dq * 4];
            acc0 = fmaf(qv.x, ka.x, acc0); acc0 = fmaf(qv.y, ka.y, acc0);
            acc0 = fmaf(qv.z, ka.z, acc0); acc0 = fmaf(qv.w, ka.w, acc0);
            acc1 = fmaf(qv.x, kb.x, acc1); acc1 = fmaf(qv.y, kb.y, acc1);
            acc1 = fmaf(qv.z, kb.z, acc1); acc1 = fmaf(qv.w, kb.w, acc1);
        }

        const float s0  = acc0 * 0.125f;
        const float s1  = acc1 * 0.125f;
        const float Dv0 = Drow[mbase + ms];
        const float Dv1 = Drow[mbase + ms + 16];
        float mix0 = b2_, mix1 = b2_;
#pragma unroll
        for (int c = 0; c < HID; ++c) {
            const float h0 = fmaf(s0, w1d_[c], fmaf(Dv0, w1s_[c], b1_[c]));
            const float h1 = fmaf(s1, w1d_[c], fmaf(Dv1, w1s_[c], b1_[c]));
            mix0 = fmaf(fmaxf(h0, 0.f), w2_[c], mix0);
            mix1 = fmaf(fmaxf(h1, 0.f), w2_[c], mix1);
        }
        scores[r][mbase + ms]      = mix0;
        scores[r][mbase + ms + 16] = mix1;
        __syncthreads();
    }

    // ---- row softmax: 16 lanes per row, shuffle butterfly ----
    {
        float mx = -1e30f;
#pragma unroll
        for (int j = 0; j < TM / 16; ++j)
            mx = fmaxf(mx, scores[r][ms + 16 * j]);
#pragma unroll
        for (int off = 1; off < 16; off <<= 1)
            mx = fmaxf(mx, __shfl_xor(mx, off, 64));

        float sum = 0.f;
#pragma unroll
        for (int j = 0; j < TM / 16; ++j) {
            const int m = ms + 16 * j;
            const float e = __expf(scores[r][m] - mx);
            scores[r][m] = e;
            sum += e;
        }
#pragma unroll
        for (int off = 1; off < 16; off <<= 1)
            sum += __shfl_xor(sum, off, 64);
        if (ms == 0) rowinv[r] = 1.0f / sum;
    }
    __syncthreads();

    // ---- PV: thread = (d, 4 rows); coalesced v reads ----
    {
        const int d  = tid & 63;
        const int rb = tid >> 6;   // 0..3
        float acc[4] = {0.f, 0.f, 0.f, 0.f};
        const float* vb = v + kbase + d;
        for (int m4 = 0; m4 < TM / 4; ++m4) {
            float vv0 = vb[(size_t)(m4 * 4 + 0) * DD];
            float vv1 = vb[(size_t)(m4 * 4 + 1) * DD];
            float vv2 = vb[(size_t)(m4 * 4 + 2) * DD];
            float vv3 = vb[(size_t)(m4 * 4 + 3) * DD];
#pragma unroll
            for (int i = 0; i < 4; ++i) {
                const int r2 = rb + 4 * i;
                const float4 wv = *(const float4*)&scores[r2][m4 * 4];
                acc[i] = fmaf(wv.x, vv0, acc[i]);
                acc[i] = fmaf(wv.y, vv1, acc[i]);
                acc[i] = fmaf(wv.z, vv2, acc[i]);
                acc[i] = fmaf(wv.w, vv3, acc[i]);
            }
        }
#pragma unroll
        for (int i = 0; i < 4; ++i) {
            const int r2 = rb + 4 * i;
            out[((size_t)b * TQ + t0 + r2) * (NH * DD) + (size_t)h * DD + d] =
                acc[i] * rowinv[r2];
        }
    }
}

extern "C" void kernel_launch(void* const* d_in, const int* in_sizes, int n_in,
                              void* d_out, int out_size, void* d_ws, size_t ws_size,
                              hipStream_t stream) {
    const float* q   = (const float*)d_in[0];
    const float* k   = (const float*)d_in[1];
    const float* v   = (const float*)d_in[2];
    const float* dtm = (const float*)d_in[3];
    const float* m1w = (const float*)d_in[4];
    const float* m1b = (const float*)d_in[5];
    const float* m2w = (const float*)d_in[6];
    const float* m2b = (const float*)d_in[7];
    float* out = (float*)d_out;

    dim3 grid(BATCH * NH * (TQ / TT));   // 2048 workgroups
    dim3 block(256);
    msmha_kernel<<<grid, block, 0, stream>>>(q, k, v, dtm, m1w, m1b, m2w, m2b, out);
}

// Round 2
// 132.573 us; speedup vs baseline: 1.5848x; 1.5848x over previous
//
#include <hip/hip_runtime.h>
#include <stdint.h>

typedef __attribute__((ext_vector_type(8))) short short8;
typedef __attribute__((ext_vector_type(4))) float floatx4;

#define MFMA(a, b, c) __builtin_amdgcn_mfma_f32_16x16x32_bf16(a, b, c, 0, 0, 0)

union Frag { uint32_t u[4]; short8 s; };

// split fp32 x into hi=bf16(trunc), lo=bf16(trunc of exact residual); pack two
// values' bf16 halves into one dword (a -> low16, b -> high16).
__device__ __forceinline__ void packsplit(float a, float b, uint32_t& hi, uint32_t& lo) {
    uint32_t ua = __float_as_uint(a), ub = __float_as_uint(b);
    uint32_t ha = ua & 0xFFFF0000u, hb = ub & 0xFFFF0000u;
    float ra = a - __uint_as_float(ha);   // exact in fp32
    float rb = b - __uint_as_float(hb);
    hi = (ha >> 16) | hb;
    lo = (__float_as_uint(ra) >> 16) | (__float_as_uint(rb) & 0xFFFF0000u);
}

// LDS dword offsets
// QK phase: K_hi[128 rows x 36dw] @0, K_lo @4608   (rows padded 64->72 bf16)
// PV phase: Vt_hi[64 x 68dw] @0, Vt_lo @4352, P_hi[64 x 68dw] @8704, P_lo @13056
#define KHI 0
#define KLO 4608
#define VTHI 0
#define VTLO 4352
#define PHI 8704
#define PLO 13056

__global__ __launch_bounds__(256, 2)
void msmha_mfma(const float* __restrict__ qg, const float* __restrict__ kg,
                const float* __restrict__ vg, const float* __restrict__ Dg,
                const float* __restrict__ m1w, const float* __restrict__ m1b,
                const float* __restrict__ m2w, const float* __restrict__ m2b,
                float* __restrict__ outg) {
    __shared__ __align__(16) uint32_t sm[17408];   // 68 KiB
    __shared__ __align__(16) float wlds[68];

    const int tid  = threadIdx.x;
    const int w    = tid >> 6;        // wave id: 16 t-rows each
    const int lane = tid & 63;
    const int col  = lane & 15;
    const int quad = lane >> 4;

    const int bid = blockIdx.x;
    const int wgT = bid & 7;          // 8 T-tiles of 64
    const int bh  = bid >> 3;
    const int h   = bh & 15;
    const int b   = bh >> 4;
    const int t0g = wgT * 64;

    const size_t base = (size_t)bh * 512 * 64;

    // MLP weights -> LDS, interleaved {w1_dot, w1_dist, b1, w2} per channel
    if (tid < 16) {
        wlds[4 * tid + 0] = m1w[h * 32 + tid];
        wlds[4 * tid + 1] = m1w[h * 32 + 16 + tid];
        wlds[4 * tid + 2] = m1b[h * 16 + tid];
        wlds[4 * tid + 3] = m2w[h * 16 + tid];
    }
    if (tid == 16) wlds[64] = m2b[h];

    // Q fragments (B-operand: lane col = t-row, k = quad*8+j), split bf16
    Frag qh[2], ql[2];
    {
        const float* qrow = qg + base + (size_t)(t0g + w * 16 + col) * 64;
#pragma unroll
        for (int ks = 0; ks < 2; ++ks) {
            const float4 f0 = *(const float4*)(qrow + ks * 32 + quad * 8);
            const float4 f1 = *(const float4*)(qrow + ks * 32 + quad * 8 + 4);
            packsplit(f0.x, f0.y, qh[ks].u[0], ql[ks].u[0]);
            packsplit(f0.z, f0.w, qh[ks].u[1], ql[ks].u[1]);
            packsplit(f1.x, f1.y, qh[ks].u[2], ql[ks].u[2]);
            packsplit(f1.z, f1.w, qh[ks].u[3], ql[ks].u[3]);
        }
    }

    floatx4 accA[32];   // S^T scores: lane holds t=col, m = mc*128 + mt*16 + quad*4 + r

    const float* Dbase = Dg + ((size_t)b * 512 + t0g + w * 16 + col) * 512 + quad * 4;

    // ================= QK^T + fused MLP, chunks of 128 m =================
#pragma unroll
    for (int mc = 0; mc < 4; ++mc) {
        __syncthreads();
        // stage K chunk 128x64 as split bf16 (rows padded to 72 elems)
#pragma unroll
        for (int it = 0; it < 8; ++it) {
            const int i  = tid + it * 256;
            const int ml = i >> 4, k4 = i & 15;
            const float4 f = *(const float4*)(kg + base + (size_t)(mc * 128 + ml) * 64 + k4 * 4);
            uint32_t h0, l0, h1, l1;
            packsplit(f.x, f.y, h0, l0);
            packsplit(f.z, f.w, h1, l1);
            *(uint2*)(sm + KHI + ml * 36 + 2 * k4) = make_uint2(h0, h1);
            *(uint2*)(sm + KLO + ml * 36 + 2 * k4) = make_uint2(l0, l1);
        }
        __syncthreads();

        // D_TM loads: contiguous float4 per tile (hidden under MFMAs)
        float4 dv[8];
#pragma unroll
        for (int mt = 0; mt < 8; ++mt)
            dv[mt] = *(const float4*)(Dbase + mc * 128 + mt * 16);

        // S^T = K·Q^T via split-bf16 (hi·hi + hi·lo + lo·hi)
#pragma unroll
        for (int mt = 0; mt < 8; ++mt) {
            floatx4 acc = {0.f, 0.f, 0.f, 0.f};
#pragma unroll
            for (int ks = 0; ks < 2; ++ks) {
                const int ro = (mt * 16 + col) * 36 + 16 * ks + 4 * quad;
                Frag ah, al;
                ah.s = *(short8*)(sm + KHI + ro);
                al.s = *(short8*)(sm + KLO + ro);
                acc = MFMA(ah.s, qh[ks].s, acc);
                acc = MFMA(ah.s, ql[ks].s, acc);
                acc = MFMA(al.s, qh[ks].s, acc);
            }
            accA[mc * 8 + mt] = acc;
        }

        // fused per-element MLP: mix = b2 + sum_c w2 relu(s*w1d + D*w1s + b1)
        float mix[32];
        const float b2v = wlds[64];
#pragma unroll
        for (int mt = 0; mt < 8; ++mt)
#pragma unroll
            for (int r = 0; r < 4; ++r) {
                accA[mc * 8 + mt][r] *= 0.125f;   // 1/sqrt(64)
                mix[mt * 4 + r] = b2v;
            }
#pragma unroll 1
        for (int c = 0; c < 16; ++c) {
            const float4 wv = *(const float4*)(wlds + 4 * c);
#pragma unroll
            for (int mt = 0; mt < 8; ++mt) {
                const float4 dd = dv[mt];
                const float dr[4] = {dd.x, dd.y, dd.z, dd.w};
#pragma unroll
                for (int r = 0; r < 4; ++r) {
                    const float hh = fmaf(accA[mc * 8 + mt][r], wv.x, fmaf(dr[r], wv.y, wv.z));
                    mix[mt * 4 + r] = fmaf(fmaxf(hh, 0.f), wv.w, mix[mt * 4 + r]);
                }
            }
        }
#pragma unroll
        for (int mt = 0; mt < 8; ++mt)
#pragma unroll
            for (int r = 0; r < 4; ++r)
                accA[mc * 8 + mt][r] = mix[mt * 4 + r];
    }

    // ================= softmax over m, fully in registers =================
    float mx = -3.4e38f;
#pragma unroll
    for (int i = 0; i < 32; ++i)
#pragma unroll
        for (int r = 0; r < 4; ++r) mx = fmaxf(mx, accA[i][r]);
    mx = fmaxf(mx, __shfl_xor(mx, 16, 64));
    mx = fmaxf(mx, __shfl_xor(mx, 32, 64));
    float sum = 0.f;
#pragma unroll
    for (int i = 0; i < 32; ++i)
#pragma unroll
        for (int r = 0; r < 4; ++r) {
            const float e = __expf(accA[i][r] - mx);
            accA[i][r] = e;
            sum += e;
        }
    sum += __shfl_xor(sum, 16, 64);
    sum += __shfl_xor(sum, 32, 64);
    const float rinv = 1.f / sum;
#pragma unroll
    for (int i = 0; i < 32; ++i)
#pragma unroll
        for (int r = 0; r < 4; ++r) accA[i][r] *= rinv;

    // ================= PV via MFMA, chunks of 128 m =================
    floatx4 oacc[4];
#pragma unroll
    for (int dt = 0; dt < 4; ++dt) oacc[dt] = floatx4{0.f, 0.f, 0.f, 0.f};

#pragma unroll
    for (int mc = 0; mc < 4; ++mc) {
        __syncthreads();
        // stage V^T chunk: Vt[d][m], split bf16, m-pairs packed per dword
#pragma unroll
        for (int it = 0; it < 4; ++it) {
            const int u  = tid + it * 256;
            const int d4 = u & 15, m2 = u >> 4;   // m2: 0..63 (m = 2*m2)
            const float4 f0 = *(const float4*)(vg + base + (size_t)(mc * 128 + 2 * m2) * 64 + d4 * 4);
            const float4 f1 = *(const float4*)(vg + base + (size_t)(mc * 128 + 2 * m2 + 1) * 64 + d4 * 4);
            const float a0[4] = {f0.x, f0.y, f0.z, f0.w};
            const float a1[4] = {f1.x, f1.y, f1.z, f1.w};
#pragma unroll
            for (int i = 0; i < 4; ++i) {
                uint32_t hw, lw;
                packsplit(a0[i], a1[i], hw, lw);
                sm[VTHI + (d4 * 4 + i) * 68 + m2] = hw;
                sm[VTLO + (d4 * 4 + i) * 68 + m2] = lw;
            }
        }
        // write P chunk to LDS (A-operand rows), split bf16
        {
            const int prow = (w * 16 + col) * 68;
#pragma unroll
            for (int mt = 0; mt < 8; ++mt) {
                const floatx4 pv = accA[mc * 8 + mt];
                uint32_t h0, l0, h1, l1;
                packsplit(pv[0], pv[1], h0, l0);
                packsplit(pv[2], pv[3], h1, l1);
                *(uint2*)(sm + PHI + prow + mt * 8 + 2 * quad) = make_uint2(h0, h1);
                *(uint2*)(sm + PLO + prow + mt * 8 + 2 * quad) = make_uint2(l0, l1);
            }
        }
        __syncthreads();
        // O += P·V  (A = P rows t, B = Vt rows d)
#pragma unroll
        for (int ks = 0; ks < 4; ++ks) {
            const int po = (w * 16 + col) * 68 + 16 * ks + 4 * quad;
            Frag pah, pal;
            pah.s = *(short8*)(sm + PHI + po);
            pal.s = *(short8*)(sm + PLO + po);
#pragma unroll
            for (int dt = 0; dt < 4; ++dt) {
                const int vo = (dt * 16 + col) * 68 + 16 * ks + 4 * quad;
                Frag bh, bl;
                bh.s = *(short8*)(sm + VTHI + vo);
                bl.s = *(short8*)(sm + VTLO + vo);
                oacc[dt] = MFMA(pah.s, bh.s, oacc[dt]);
                oacc[dt] = MFMA(pah.s, bl.s, oacc[dt]);
                oacc[dt] = MFMA(pal.s, bh.s, oacc[dt]);
            }
        }
    }

    // epilogue: D layout row = t_local (quad*4+r), col = d
    const size_t obase = ((size_t)b * 512 + t0g + w * 16 + quad * 4) * 1024 + h * 64 + col;
#pragma unroll
    for (int dt = 0; dt < 4; ++dt)
#pragma unroll
        for (int r = 0; r < 4; ++r)
            outg[obase + (size_t)r * 1024 + dt * 16] = oacc[dt][r];
}

extern "C" void kernel_launch(void* const* d_in, const int* in_sizes, int n_in,
                              void* d_out, int out_size, void* d_ws, size_t ws_size,
                              hipStream_t stream) {
    const float* q   = (const float*)d_in[0];
    const float* k   = (const float*)d_in[1];
    const float* v   = (const float*)d_in[2];
    const float* dtm = (const float*)d_in[3];
    const float* m1w = (const float*)d_in[4];
    const float* m1b = (const float*)d_in[5];
    const float* m2w = (const float*)d_in[6];
    const float* m2b = (const float*)d_in[7];
    float* out = (float*)d_out;

    dim3 grid(4 * 16 * 8);   // 512 workgroups: (b,h) x 8 T-tiles
    dim3 block(256);
    msmha_mfma<<<grid, block, 0, stream>>>(q, k, v, dtm, m1w, m1b, m2w, m2b, out);
}